// Round 6
// baseline (390.247 us; speedup 1.0000x reference)
//
#include <hip/hip_runtime.h>
#include <math.h>

#define N_ATOMS 4096
#define L_WORDS 65536
#define DD 10
#define HALO 11

#define CONV_BLOCKS 256
#define CONV_BLOCK 256
#define RPW 8                     // rows per wave
#define RPB 32                    // rows per block (4 waves)
#define QCOLS 1024                // columns per quarter
#define TOTAL_BLOCKS 768          // 256 conv + 512 gnn = 3 blocks/CU
#define ATT_BLOCKS 64
#define STASH 10240               // LDS offset of reduction stash (floats)

// ---------------------------------------------------------------------------
// K0: embedding gather -> xs0 planes + hs0 = relu(W0 xs0 + b0) planes.
// The random emb_fp gather happens ONCE here (round-4 F0: in-block replicated
// cold gather saturates the memory system).
// ---------------------------------------------------------------------------
__global__ __launch_bounds__(128) void gnn_embed(
    const int* __restrict__ fp, const float* __restrict__ embed_fp,
    const float* __restrict__ Wg, const float* __restrict__ bg,
    float* __restrict__ xs, float* __restrict__ hs)
{
    const int n = blockIdx.x * 128 + threadIdx.x;   // grid 32x128 = 4096
    float x[DD];
    const float* e = embed_fp + (size_t)fp[n] * DD;
    #pragma unroll
    for (int d = 0; d < DD; ++d) x[d] = e[d];
    #pragma unroll
    for (int d = 0; d < DD; ++d) xs[d * N_ATOMS + n] = x[d];
    #pragma unroll
    for (int d = 0; d < DD; ++d) {
        float v = bg[d];
        #pragma unroll
        for (int k = 0; k < DD; ++k) v += Wg[d * DD + k] * x[k];
        hs[d * N_ATOMS + n] = fmaxf(v, 0.f);
    }
}

// ---------------------------------------------------------------------------
// conv stage: one CNN layer over this block's 256 words.
// If hpb != null, also fuses hp = relu(Wa·relu(acc)+ba) for its own words.
// ---------------------------------------------------------------------------
__device__ __forceinline__ void conv_stage(
    float* sh, const int tid, const int bx,
    const float* __restrict__ tin, const int* __restrict__ words,
    const float* __restrict__ embed_word, const float* __restrict__ w,
    const float* __restrict__ bptr, float* __restrict__ tout,
    const float* __restrict__ Wa, const float* __restrict__ ba,
    float* __restrict__ hpb)
{
    const int l0 = bx * CONV_BLOCK;
    for (int idx = tid; idx < (CONV_BLOCK + 2 * HALO) * DD; idx += CONV_BLOCK) {
        int rr = idx / DD, d = idx - rr * DD;
        int gr = l0 - HALO + rr;
        float v = 0.f;
        if (gr >= 0 && gr < L_WORDS) {
            if (tin) v = tin[(size_t)gr * DD + d];
            else     v = embed_word[(size_t)words[gr] * DD + d];
        }
        sh[rr * 11 + d] = v;
    }
    __syncthreads();

    const float bias = *bptr;
    float acc[DD];
    #pragma unroll
    for (int d = 0; d < DD; ++d) acc[d] = bias;
    for (int i = 0; i < 23; ++i) {
        float row[DD];
        const float* sr = &sh[(tid + i) * 11];
        #pragma unroll
        for (int c = 0; c < DD; ++c) row[c] = sr[c];
        #pragma unroll
        for (int d = 0; d < DD; ++d) {
            #pragma unroll
            for (int c = 0; c < DD; ++c)
                acc[d] += row[c] * w[i * 23 + (c - d + 11)];
        }
    }
    const int l = l0 + tid;
    if (tout) {
        #pragma unroll
        for (int d = 0; d < DD; ++d)
            tout[(size_t)l * DD + d] = fmaxf(acc[d], 0.f);
    }
    if (hpb) {
        float xsp[DD];
        #pragma unroll
        for (int d = 0; d < DD; ++d) xsp[d] = fmaxf(acc[d], 0.f);
        #pragma unroll
        for (int d = 0; d < DD; ++d) {
            float v = ba[d];
            #pragma unroll
            for (int k = 0; k < DD; ++k) v += Wa[d * DD + k] * xsp[k];
            hpb[(size_t)l * DD + d] = fmaxf(v, 0.f);
        }
    }
}

// ---------------------------------------------------------------------------
// gnn stage: A@hs partial over a 1024-column quarter.
// Latency-stall fixes this round:
//  (a) first 8 A-loads issued at ENTRY (overlap stage phase + barrier)
//  (b) register double-buffer a_cur/a_nxt: FMAs of it run with it+1's
//      8 loads in flight (compiler emits counted vmcnt, not a drain)
//  (c) reduction stash moved to disjoint LDS region [STASH..] -> one less
//      __syncthreads (hs region never overwritten)
// ---------------------------------------------------------------------------
__device__ __forceinline__ void gnn_stage(
    float* sh, const int tid, const int b,
    const float* __restrict__ hs_in,
    const float* __restrict__ xs_in, const float* __restrict__ part_in,
    const float* __restrict__ Wg, const float* __restrict__ bg,
    float* __restrict__ xs_out,
    const float* __restrict__ A, float* __restrict__ part_out)
{
    const int wave = tid >> 6, lane = tid & 63;
    const int q = b & 3, rg = b >> 2;
    const int qbase = q * QCOLS;

    // ---- (a) issue first A-load batch immediately ----
    const int r0 = rg * RPB + wave * RPW;
    const float4* A4 = (const float4*)(A + (size_t)r0 * N_ATOMS) + q * (QCOLS / 4);
    float4 a_cur[RPW];
    #pragma unroll
    for (int r = 0; r < RPW; ++r) a_cur[r] = A4[r * (N_ATOMS / 4) + lane];

    if (hs_in) {
        // ---- L0: coalesced plane copy of hs quarter ----
        const float4* h4 = (const float4*)hs_in;
        float4* shw = (float4*)sh;
        #pragma unroll
        for (int d = 0; d < DD; ++d)
            shw[d * 256 + tid] = h4[d * (N_ATOMS / 4) + q * 256 + tid];
    } else {
        // ---- L1/L2: in-block prep from xs + parts (dense planes) ----
        for (int j = 0; j < 4; ++j) {
            const int lc = j * 256 + tid;
            const int n = qbase + lc;
            float x[DD];
            #pragma unroll
            for (int d = 0; d < DD; ++d) {
                float v = xs_in[d * N_ATOMS + n];
                #pragma unroll
                for (int qq = 0; qq < 4; ++qq)
                    v += part_in[((size_t)qq * DD + d) * N_ATOMS + n];
                x[d] = v;
            }
            if (rg == 0) {
                #pragma unroll
                for (int d = 0; d < DD; ++d) xs_out[d * N_ATOMS + n] = x[d];
            }
            #pragma unroll
            for (int d = 0; d < DD; ++d) {
                float v = bg[d];
                #pragma unroll
                for (int k = 0; k < DD; ++k) v += Wg[d * DD + k] * x[k];
                sh[d * QCOLS + lc] = fmaxf(v, 0.f);
            }
        }
    }
    __syncthreads();

    const float4* sh4 = (const float4*)sh;

    float acc[RPW][DD];
    #pragma unroll
    for (int r = 0; r < RPW; ++r)
        #pragma unroll
        for (int d = 0; d < DD; ++d) acc[r][d] = 0.f;

    // ---- (b) software-pipelined main loop ----
    #pragma unroll 1
    for (int it = 0; it < 4; ++it) {
        const int cb = it * 64 + lane;
        float4 a_nxt[RPW];
        if (it < 3) {
            #pragma unroll
            for (int r = 0; r < RPW; ++r)
                a_nxt[r] = A4[r * (N_ATOMS / 4) + cb + 64];
        }
        #pragma unroll
        for (int d = 0; d < DD; ++d) {
            float4 h = sh4[d * 256 + cb];
            #pragma unroll
            for (int r = 0; r < RPW; ++r) {
                acc[r][d] += a_cur[r].x * h.x;
                acc[r][d] += a_cur[r].y * h.y;
                acc[r][d] += a_cur[r].z * h.z;
                acc[r][d] += a_cur[r].w * h.w;
            }
        }
        if (it < 3) {
            #pragma unroll
            for (int r = 0; r < RPW; ++r) a_cur[r] = a_nxt[r];
        }
    }

    // ---- reduction: 3 xor steps within 8-lane groups ----
    #pragma unroll
    for (int m = 1; m <= 4; m <<= 1) {
        #pragma unroll
        for (int r = 0; r < RPW; ++r)
            #pragma unroll
            for (int d = 0; d < DD; ++d)
                acc[r][d] += __shfl_xor(acc[r][d], m, 64);
    }

    // (c) leaders stash into disjoint region: no barrier needed before this
    if ((lane & 7) == 0) {
        const int g = lane >> 3;
        float* dst = &sh[STASH + (wave * 8 + g) * 80];
        #pragma unroll
        for (int r = 0; r < RPW; ++r)
            #pragma unroll
            for (int d = 0; d < DD; ++d) dst[r * DD + d] = acc[r][d];
    }
    __syncthreads();

    float* pdst = part_out + (size_t)q * DD * N_ATOMS + (size_t)rg * RPB;
    for (int o = tid; o < RPB * DD; o += 256) {
        const int d = o >> 5, rr = o & 31;
        const int w8 = rr >> 3, r = rr & 7;
        float v = 0.f;
        #pragma unroll
        for (int g = 0; g < 8; ++g)
            v += sh[STASH + (w8 * 8 + g) * 80 + r * DD + d];
        pdst[d * N_ATOMS + rr] = v;
    }
}

// ---------------------------------------------------------------------------
// F: one pipeline step. blocks [0,256): conv layer; [256,768): gnn layer.
// LDS 50 KB (40 KB hs + 10 KB stash): 3 blocks/CU = 150 KB <= 160 KB.
// ---------------------------------------------------------------------------
__global__ __launch_bounds__(256, 3) void fused_layer(
    const float* __restrict__ A, const float* __restrict__ hs_in,
    const float* __restrict__ xs_in, const float* __restrict__ part_in,
    const float* __restrict__ Wg, const float* __restrict__ bg,
    float* __restrict__ xs_out, float* __restrict__ part_out,
    const float* __restrict__ tin, const int* __restrict__ words,
    const float* __restrict__ emb_w, const float* __restrict__ wc,
    const float* __restrict__ bc, float* __restrict__ tout,
    const float* __restrict__ Wa, const float* __restrict__ ba,
    float* __restrict__ hpb)
{
    __shared__ float sh[STASH + RPB * 80];   // 10240 + 2560 floats = 50 KB
    const int tid = threadIdx.x;
    if (blockIdx.x < CONV_BLOCKS)
        conv_stage(sh, tid, blockIdx.x, tin, words, emb_w, wc, bc, tout,
                   Wa, ba, hpb);
    else
        gnn_stage(sh, tid, blockIdx.x - CONV_BLOCKS, hs_in,
                  xs_in, part_in, Wg, bg, xs_out, A, part_out);
}

// ---------------------------------------------------------------------------
// ATTN+FINAL: 64 blocks x 1024 threads (1 word/thread). Relaxed agent-scope
// atomic publication + last-block ticket election (proven rounds 4/5).
// ---------------------------------------------------------------------------
__global__ __launch_bounds__(1024) void attn_final(
    const float* __restrict__ xs2, const float* __restrict__ part2,
    const float* __restrict__ hpb,
    const float* __restrict__ Wa, const float* __restrict__ ba,
    const float* __restrict__ Wo, const float* __restrict__ bo,
    const float* __restrict__ Wi, const float* __restrict__ bi,
    float* att_part, unsigned int* ticket, float* __restrict__ out)
{
    __shared__ float red[16][DD];
    __shared__ float shc[DD];
    __shared__ float cat[20];
    __shared__ int islast;
    const int tid = threadIdx.x, wave = tid >> 6, lane = tid & 63;

    // ---- comp (redundant per block; L3-resident reads) ----
    float c[DD];
    #pragma unroll
    for (int d = 0; d < DD; ++d) c[d] = 0.f;
    #pragma unroll
    for (int s = 0; s < 4; ++s) {
        const int n = s * 1024 + tid;
        #pragma unroll
        for (int d = 0; d < DD; ++d) {
            float v = xs2[d * N_ATOMS + n];
            #pragma unroll
            for (int qq = 0; qq < 4; ++qq)
                v += part2[((size_t)qq * DD + d) * N_ATOMS + n];
            c[d] += v;
        }
    }
    #pragma unroll
    for (int m = 32; m >= 1; m >>= 1) {
        #pragma unroll
        for (int d = 0; d < DD; ++d) c[d] += __shfl_xor(c[d], m, 64);
    }
    if (lane == 0) {
        #pragma unroll
        for (int d = 0; d < DD; ++d) red[wave][d] = c[d];
    }
    __syncthreads();
    if (tid < DD) {
        float v = 0.f;
        #pragma unroll
        for (int w = 0; w < 16; ++w) v += red[w][tid];
        shc[tid] = v * (1.f / N_ATOMS);
    }
    __syncthreads();

    // ---- attention for this thread's word ----
    float h[DD];
    #pragma unroll
    for (int d = 0; d < DD; ++d) {
        float v = ba[d];
        #pragma unroll
        for (int k = 0; k < DD; ++k) v += Wa[d * DD + k] * shc[k];
        h[d] = fmaxf(v, 0.f);
    }
    const int w_ = blockIdx.x * 1024 + tid;
    float hp[DD], dotv = 0.f;
    #pragma unroll
    for (int d = 0; d < DD; ++d) {
        hp[d] = hpb[(size_t)w_ * DD + d];
        dotv += h[d] * hp[d];
    }
    const float wgt = tanhf(dotv);
    float y[DD];
    #pragma unroll
    for (int d = 0; d < DD; ++d) y[d] = wgt * hp[d];
    #pragma unroll
    for (int m = 32; m >= 1; m >>= 1) {
        #pragma unroll
        for (int d = 0; d < DD; ++d) y[d] += __shfl_xor(y[d], m, 64);
    }
    __syncthreads();
    if (lane == 0) {
        #pragma unroll
        for (int d = 0; d < DD; ++d) red[wave][d] = y[d];
    }
    __syncthreads();
    if (tid < DD) {
        float v = 0.f;
        #pragma unroll
        for (int w = 0; w < 16; ++w) v += red[w][tid];
        __hip_atomic_store(att_part + blockIdx.x * DD + tid, v,
                           __ATOMIC_RELAXED, __HIP_MEMORY_SCOPE_AGENT);
    }
    __syncthreads();   // drains each wave's vmcnt -> stores globally visible

    if (tid == 0) {
        unsigned prev = __hip_atomic_fetch_add(ticket, 1u, __ATOMIC_RELAXED,
                                               __HIP_MEMORY_SCOPE_AGENT);
        islast = (prev == ATT_BLOCKS - 1);
    }
    __syncthreads();
    if (!islast) return;
    asm volatile("" ::: "memory");

    // ---- final: reduce 64 partials + MLP (last block only) ----
    float a[DD];
    #pragma unroll
    for (int d = 0; d < DD; ++d) a[d] = 0.f;
    if (tid < ATT_BLOCKS) {
        #pragma unroll
        for (int d = 0; d < DD; ++d)
            a[d] = __hip_atomic_load(att_part + tid * DD + d,
                                     __ATOMIC_RELAXED, __HIP_MEMORY_SCOPE_AGENT);
    }
    if (wave == 0) {
        #pragma unroll
        for (int m = 32; m >= 1; m >>= 1) {
            #pragma unroll
            for (int d = 0; d < DD; ++d) a[d] += __shfl_xor(a[d], m, 64);
        }
    }
    if (tid == 0) {
        #pragma unroll
        for (int d = 0; d < DD; ++d) cat[DD + d] = a[d] * (1.f / L_WORDS);
    }
    if (tid < DD) cat[tid] = shc[tid];   // compound mean already scaled
    __syncthreads();
    for (int j = 0; j < 3; ++j) {
        float v = 0.f;
        if (tid < 20) {
            v = bo[j * 20 + tid];
            for (int k = 0; k < 20; ++k) v += Wo[j * 400 + tid * 20 + k] * cat[k];
        }
        __syncthreads();
        if (tid < 20) cat[tid] = fmaxf(v, 0.f);
        __syncthreads();
    }
    if (tid < 2) {
        float v = bi[tid];
        for (int k = 0; k < 20; ++k) v += Wi[tid * 20 + k] * cat[k];
        out[tid] = v;
    }
}

// ---------------------------------------------------------------------------
extern "C" void kernel_launch(void* const* d_in, const int* in_sizes, int n_in,
                              void* d_out, int out_size, void* d_ws, size_t ws_size,
                              hipStream_t stream)
{
    const int*   fp     = (const int*)d_in[0];
    const float* A      = (const float*)d_in[1];
    const int*   words  = (const int*)d_in[2];
    const float* emb_fp = (const float*)d_in[3];
    const float* emb_w  = (const float*)d_in[4];
    const float* Wg     = (const float*)d_in[5];   // [3][10][10]
    const float* bg     = (const float*)d_in[6];   // [3][10]
    const float* Wc     = (const float*)d_in[7];   // [3][529]
    const float* bc     = (const float*)d_in[8];   // [3]
    const float* Wa     = (const float*)d_in[9];   // [10][10]
    const float* ba     = (const float*)d_in[10];  // [10]
    const float* Wo     = (const float*)d_in[11];  // [3][20][20]
    const float* bo     = (const float*)d_in[12];  // [3][20]
    const float* Wi     = (const float*)d_in[13];  // [2][20]
    const float* bi     = (const float*)d_in[14];  // [2]
    float* out = (float*)d_out;
    float* ws  = (float*)d_ws;

    float* xs0   = ws;                       // 40960   SoA [10][4096]
    float* xs1   = ws + 40960;               // 40960
    float* xs2   = ws + 81920;               // 40960
    float* hs0   = ws + 122880;              // 40960   SoA planes (L0 only)
    float* part0 = ws + 163840;              // 163840  SoA [4][10][4096]
    float* part1 = ws + 327680;              // 163840
    float* part2 = ws + 491520;              // 163840
    float* ta    = ws + 655360;              // 655360
    float* tb    = ws + 1310720;             // 655360
    float* hpb   = ta;                       // alias: ta dead after F1 reads it
    float* att_part = ws + 1966080;          // 640
    unsigned int* ticket = (unsigned int*)(ws + 1966720);

    hipMemsetAsync(ticket, 0, sizeof(unsigned int), stream);

    // K0: embed gather once (tiny) -> xs0 + hs0 planes
    gnn_embed<<<N_ATOMS / 128, 128, 0, stream>>>(fp, emb_fp, Wg, bg, xs0, hs0);

    // F0: conv-L0 || gnn-L0 (stage = coalesced hs0 plane copy)
    fused_layer<<<TOTAL_BLOCKS, 256, 0, stream>>>(
        A, hs0, nullptr, nullptr, Wg, bg, nullptr, part0,
        nullptr, words, emb_w, Wc, bc, ta, nullptr, nullptr, nullptr);

    // F1: conv-L1 || gnn-L1 (prep folded in-block)
    fused_layer<<<TOTAL_BLOCKS, 256, 0, stream>>>(
        A, nullptr, xs0, part0, Wg + 100, bg + 10, xs1, part1,
        ta, words, emb_w, Wc + 529, bc + 1, tb, nullptr, nullptr, nullptr);

    // F2: conv-L2 (+ fused hp) || gnn-L2 (prep folded)
    fused_layer<<<TOTAL_BLOCKS, 256, 0, stream>>>(
        A, nullptr, xs1, part1, Wg + 200, bg + 20, xs2, part2,
        tb, words, emb_w, Wc + 1058, bc + 2, nullptr, Wa, ba, hpb);

    // ATTN (+ comp in-block, + final MLP in last-arriving block)
    attn_final<<<ATT_BLOCKS, 1024, 0, stream>>>(
        xs2, part2, hpb, Wa, ba, Wo, bo, Wi, bi, att_part, ticket, out);
}

// Round 7
// 206.275 us; speedup vs baseline: 1.8919x; 1.8919x over previous
//
#include <hip/hip_runtime.h>
#include <math.h>

#define N_ATOMS 4096
#define L_WORDS 65536
#define DD 10
#define HALO 11

#define CONV_BLOCKS 256
#define CONV_BLOCK 256
#define RPW 8                     // rows per wave
#define RPB 32                    // rows per block (4 waves)
#define QCOLS 1024                // columns per quarter
#define TOTAL_BLOCKS 768          // 256 conv + 512 gnn
#define ATT_BLOCKS 64
#define SH_FLOATS 2926            // max(conv halo 266*11, stash 2560)

// ---------------------------------------------------------------------------
// K0: embedding gather -> xs0 planes + hs0 = relu(W0 xs0 + b0) planes.
// Random emb_fp gather happens ONCE (round-4: replicated in-block cold gather
// saturates the memory system).
// ---------------------------------------------------------------------------
__global__ __launch_bounds__(128) void gnn_embed(
    const int* __restrict__ fp, const float* __restrict__ embed_fp,
    const float* __restrict__ Wg, const float* __restrict__ bg,
    float* __restrict__ xs, float* __restrict__ hs)
{
    const int n = blockIdx.x * 128 + threadIdx.x;   // grid 32x128 = 4096
    float x[DD];
    const float* e = embed_fp + (size_t)fp[n] * DD;
    #pragma unroll
    for (int d = 0; d < DD; ++d) x[d] = e[d];
    #pragma unroll
    for (int d = 0; d < DD; ++d) xs[d * N_ATOMS + n] = x[d];
    #pragma unroll
    for (int d = 0; d < DD; ++d) {
        float v = bg[d];
        #pragma unroll
        for (int k = 0; k < DD; ++k) v += Wg[d * DD + k] * x[k];
        hs[d * N_ATOMS + n] = fmaxf(v, 0.f);
    }
}

// ---------------------------------------------------------------------------
// K_prep: xs_{i+1} = xs_i + sum_q part_i ; hs_{i+1} = relu(W xs + b).
// All SoA planes -> fully coalesced. Tiny (64 waves), runs once per layer.
// ---------------------------------------------------------------------------
__global__ __launch_bounds__(128) void gnn_prep(
    const float* __restrict__ xs_in, const float* __restrict__ part,
    const float* __restrict__ Wg, const float* __restrict__ bg,
    float* __restrict__ xs_out, float* __restrict__ hs)
{
    const int n = blockIdx.x * 128 + threadIdx.x;   // grid 32x128
    float x[DD];
    #pragma unroll
    for (int d = 0; d < DD; ++d) {
        float v = xs_in[d * N_ATOMS + n];
        #pragma unroll
        for (int q = 0; q < 4; ++q)
            v += part[((size_t)q * DD + d) * N_ATOMS + n];
        x[d] = v;
        xs_out[d * N_ATOMS + n] = v;
    }
    #pragma unroll
    for (int d = 0; d < DD; ++d) {
        float v = bg[d];
        #pragma unroll
        for (int k = 0; k < DD; ++k) v += Wg[d * DD + k] * x[k];
        hs[d * N_ATOMS + n] = fmaxf(v, 0.f);
    }
}

// ---------------------------------------------------------------------------
// conv stage: one CNN layer over this block's 256 words.
// If hpb != null, also fuses hp = relu(Wa·relu(acc)+ba) for its own words.
// ---------------------------------------------------------------------------
__device__ __forceinline__ void conv_stage(
    float* sh, const int tid, const int bx,
    const float* __restrict__ tin, const int* __restrict__ words,
    const float* __restrict__ embed_word, const float* __restrict__ w,
    const float* __restrict__ bptr, float* __restrict__ tout,
    const float* __restrict__ Wa, const float* __restrict__ ba,
    float* __restrict__ hpb)
{
    const int l0 = bx * CONV_BLOCK;
    for (int idx = tid; idx < (CONV_BLOCK + 2 * HALO) * DD; idx += CONV_BLOCK) {
        int rr = idx / DD, d = idx - rr * DD;
        int gr = l0 - HALO + rr;
        float v = 0.f;
        if (gr >= 0 && gr < L_WORDS) {
            if (tin) v = tin[(size_t)gr * DD + d];
            else     v = embed_word[(size_t)words[gr] * DD + d];
        }
        sh[rr * 11 + d] = v;
    }
    __syncthreads();

    const float bias = *bptr;
    float acc[DD];
    #pragma unroll
    for (int d = 0; d < DD; ++d) acc[d] = bias;
    for (int i = 0; i < 23; ++i) {
        float row[DD];
        const float* sr = &sh[(tid + i) * 11];
        #pragma unroll
        for (int c = 0; c < DD; ++c) row[c] = sr[c];
        #pragma unroll
        for (int d = 0; d < DD; ++d) {
            #pragma unroll
            for (int c = 0; c < DD; ++c)
                acc[d] += row[c] * w[i * 23 + (c - d + 11)];
        }
    }
    const int l = l0 + tid;
    if (tout) {
        #pragma unroll
        for (int d = 0; d < DD; ++d)
            tout[(size_t)l * DD + d] = fmaxf(acc[d], 0.f);
    }
    if (hpb) {
        float xsp[DD];
        #pragma unroll
        for (int d = 0; d < DD; ++d) xsp[d] = fmaxf(acc[d], 0.f);
        #pragma unroll
        for (int d = 0; d < DD; ++d) {
            float v = ba[d];
            #pragma unroll
            for (int k = 0; k < DD; ++k) v += Wa[d * DD + k] * xsp[k];
            hpb[(size_t)l * DD + d] = fmaxf(v, 0.f);
        }
    }
}

// ---------------------------------------------------------------------------
// gnn stage: A@hs partial over a 1024-column quarter.
// This round: NO LDS hs tile — h read straight from the global SoA planes
// (160 KB total, L2-resident, coalesced float4 per wave: same addresses the
// old plane-copy used). Removes the stage phase + one barrier, and cuts
// LDS/block 50KB -> 11.7KB so occupancy rises 3 -> 4 blocks/CU.
// Load structure = round-5 (proven spill-free; round-6 prefetch spilled).
// ---------------------------------------------------------------------------
__device__ __forceinline__ void gnn_stage(
    float* sh, const int tid, const int b,
    const float* __restrict__ hs,        // SoA [10][4096]
    const float* __restrict__ A, float* __restrict__ part_out)
{
    const int wave = tid >> 6, lane = tid & 63;
    const int q = b & 3, rg = b >> 2;

    const int r0 = rg * RPB + wave * RPW;
    const float4* A4 = (const float4*)(A + (size_t)r0 * N_ATOMS) + q * (QCOLS / 4);
    const float4* h4 = (const float4*)hs + q * (QCOLS / 4);   // plane stride 1024

    float acc[RPW][DD];
    #pragma unroll
    for (int r = 0; r < RPW; ++r)
        #pragma unroll
        for (int d = 0; d < DD; ++d) acc[r][d] = 0.f;

    #pragma unroll 1
    for (int it = 0; it < 4; ++it) {
        const int cb = it * 64 + lane;
        float4 a[RPW];
        #pragma unroll
        for (int r = 0; r < RPW; ++r) a[r] = A4[r * (N_ATOMS / 4) + cb];
        #pragma unroll
        for (int d = 0; d < DD; ++d) {
            float4 h = h4[d * (N_ATOMS / 4) + cb];   // L2 hit, coalesced
            #pragma unroll
            for (int r = 0; r < RPW; ++r) {
                acc[r][d] += a[r].x * h.x;
                acc[r][d] += a[r].y * h.y;
                acc[r][d] += a[r].z * h.z;
                acc[r][d] += a[r].w * h.w;
            }
        }
    }

    // ---- reduction: 3 xor steps within 8-lane groups ----
    #pragma unroll
    for (int m = 1; m <= 4; m <<= 1) {
        #pragma unroll
        for (int r = 0; r < RPW; ++r)
            #pragma unroll
            for (int d = 0; d < DD; ++d)
                acc[r][d] += __shfl_xor(acc[r][d], m, 64);
    }

    // leaders stash partials: [wave][group][80]
    if ((lane & 7) == 0) {
        const int g = lane >> 3;
        float* dst = &sh[(wave * 8 + g) * 80];
        #pragma unroll
        for (int r = 0; r < RPW; ++r)
            #pragma unroll
            for (int d = 0; d < DD; ++d) dst[r * DD + d] = acc[r][d];
    }
    __syncthreads();

    // block finish: 320 outputs (10 planes x 32 rows), SoA coalesced write
    float* pdst = part_out + (size_t)q * DD * N_ATOMS + (size_t)rg * RPB;
    for (int o = tid; o < RPB * DD; o += 256) {
        const int d = o >> 5, rr = o & 31;
        const int w8 = rr >> 3, r = rr & 7;
        float v = 0.f;
        #pragma unroll
        for (int g = 0; g < 8; ++g) v += sh[(w8 * 8 + g) * 80 + r * DD + d];
        pdst[d * N_ATOMS + rr] = v;
    }
}

// ---------------------------------------------------------------------------
// F: one pipeline step. blocks [0,256): conv layer; [256,768): gnn layer.
// LDS 11.7 KB -> 4 blocks/CU at VGPR<=~128 (16 waves/CU).
// ---------------------------------------------------------------------------
__global__ __launch_bounds__(256, 3) void fused_layer(
    const float* __restrict__ A, const float* __restrict__ hs,
    float* __restrict__ part_out,
    const float* __restrict__ tin, const int* __restrict__ words,
    const float* __restrict__ emb_w, const float* __restrict__ wc,
    const float* __restrict__ bc, float* __restrict__ tout,
    const float* __restrict__ Wa, const float* __restrict__ ba,
    float* __restrict__ hpb)
{
    __shared__ float sh[SH_FLOATS];      // 11.7 KB
    const int tid = threadIdx.x;
    if (blockIdx.x < CONV_BLOCKS)
        conv_stage(sh, tid, blockIdx.x, tin, words, emb_w, wc, bc, tout,
                   Wa, ba, hpb);
    else
        gnn_stage(sh, tid, blockIdx.x - CONV_BLOCKS, hs, A, part_out);
}

// ---------------------------------------------------------------------------
// ATTN+FINAL: 64 blocks x 1024 threads (1 word/thread). Relaxed agent-scope
// atomic publication + last-block ticket election (proven rounds 4/5).
// ---------------------------------------------------------------------------
__global__ __launch_bounds__(1024) void attn_final(
    const float* __restrict__ xs2, const float* __restrict__ part2,
    const float* __restrict__ hpb,
    const float* __restrict__ Wa, const float* __restrict__ ba,
    const float* __restrict__ Wo, const float* __restrict__ bo,
    const float* __restrict__ Wi, const float* __restrict__ bi,
    float* att_part, unsigned int* ticket, float* __restrict__ out)
{
    __shared__ float red[16][DD];
    __shared__ float shc[DD];
    __shared__ float cat[20];
    __shared__ int islast;
    const int tid = threadIdx.x, wave = tid >> 6, lane = tid & 63;

    // ---- comp (redundant per block; L3-resident reads) ----
    float c[DD];
    #pragma unroll
    for (int d = 0; d < DD; ++d) c[d] = 0.f;
    #pragma unroll
    for (int s = 0; s < 4; ++s) {
        const int n = s * 1024 + tid;
        #pragma unroll
        for (int d = 0; d < DD; ++d) {
            float v = xs2[d * N_ATOMS + n];
            #pragma unroll
            for (int qq = 0; qq < 4; ++qq)
                v += part2[((size_t)qq * DD + d) * N_ATOMS + n];
            c[d] += v;
        }
    }
    #pragma unroll
    for (int m = 32; m >= 1; m >>= 1) {
        #pragma unroll
        for (int d = 0; d < DD; ++d) c[d] += __shfl_xor(c[d], m, 64);
    }
    if (lane == 0) {
        #pragma unroll
        for (int d = 0; d < DD; ++d) red[wave][d] = c[d];
    }
    __syncthreads();
    if (tid < DD) {
        float v = 0.f;
        #pragma unroll
        for (int w = 0; w < 16; ++w) v += red[w][tid];
        shc[tid] = v * (1.f / N_ATOMS);
    }
    __syncthreads();

    // ---- attention for this thread's word ----
    float h[DD];
    #pragma unroll
    for (int d = 0; d < DD; ++d) {
        float v = ba[d];
        #pragma unroll
        for (int k = 0; k < DD; ++k) v += Wa[d * DD + k] * shc[k];
        h[d] = fmaxf(v, 0.f);
    }
    const int w_ = blockIdx.x * 1024 + tid;
    float hp[DD], dotv = 0.f;
    #pragma unroll
    for (int d = 0; d < DD; ++d) {
        hp[d] = hpb[(size_t)w_ * DD + d];
        dotv += h[d] * hp[d];
    }
    const float wgt = tanhf(dotv);
    float y[DD];
    #pragma unroll
    for (int d = 0; d < DD; ++d) y[d] = wgt * hp[d];
    #pragma unroll
    for (int m = 32; m >= 1; m >>= 1) {
        #pragma unroll
        for (int d = 0; d < DD; ++d) y[d] += __shfl_xor(y[d], m, 64);
    }
    __syncthreads();
    if (lane == 0) {
        #pragma unroll
        for (int d = 0; d < DD; ++d) red[wave][d] = y[d];
    }
    __syncthreads();
    if (tid < DD) {
        float v = 0.f;
        #pragma unroll
        for (int w = 0; w < 16; ++w) v += red[w][tid];
        __hip_atomic_store(att_part + blockIdx.x * DD + tid, v,
                           __ATOMIC_RELAXED, __HIP_MEMORY_SCOPE_AGENT);
    }
    __syncthreads();   // drains each wave's vmcnt -> stores globally visible

    if (tid == 0) {
        unsigned prev = __hip_atomic_fetch_add(ticket, 1u, __ATOMIC_RELAXED,
                                               __HIP_MEMORY_SCOPE_AGENT);
        islast = (prev == ATT_BLOCKS - 1);
    }
    __syncthreads();
    if (!islast) return;
    asm volatile("" ::: "memory");

    // ---- final: reduce 64 partials + MLP (last block only) ----
    float a[DD];
    #pragma unroll
    for (int d = 0; d < DD; ++d) a[d] = 0.f;
    if (tid < ATT_BLOCKS) {
        #pragma unroll
        for (int d = 0; d < DD; ++d)
            a[d] = __hip_atomic_load(att_part + tid * DD + d,
                                     __ATOMIC_RELAXED, __HIP_MEMORY_SCOPE_AGENT);
    }
    if (wave == 0) {
        #pragma unroll
        for (int m = 32; m >= 1; m >>= 1) {
            #pragma unroll
            for (int d = 0; d < DD; ++d) a[d] += __shfl_xor(a[d], m, 64);
        }
    }
    if (tid == 0) {
        #pragma unroll
        for (int d = 0; d < DD; ++d) cat[DD + d] = a[d] * (1.f / L_WORDS);
    }
    if (tid < DD) cat[tid] = shc[tid];   // compound mean already scaled
    __syncthreads();
    for (int j = 0; j < 3; ++j) {
        float v = 0.f;
        if (tid < 20) {
            v = bo[j * 20 + tid];
            for (int k = 0; k < 20; ++k) v += Wo[j * 400 + tid * 20 + k] * cat[k];
        }
        __syncthreads();
        if (tid < 20) cat[tid] = fmaxf(v, 0.f);
        __syncthreads();
    }
    if (tid < 2) {
        float v = bi[tid];
        for (int k = 0; k < 20; ++k) v += Wi[tid * 20 + k] * cat[k];
        out[tid] = v;
    }
}

// ---------------------------------------------------------------------------
extern "C" void kernel_launch(void* const* d_in, const int* in_sizes, int n_in,
                              void* d_out, int out_size, void* d_ws, size_t ws_size,
                              hipStream_t stream)
{
    const int*   fp     = (const int*)d_in[0];
    const float* A      = (const float*)d_in[1];
    const int*   words  = (const int*)d_in[2];
    const float* emb_fp = (const float*)d_in[3];
    const float* emb_w  = (const float*)d_in[4];
    const float* Wg     = (const float*)d_in[5];   // [3][10][10]
    const float* bg     = (const float*)d_in[6];   // [3][10]
    const float* Wc     = (const float*)d_in[7];   // [3][529]
    const float* bc     = (const float*)d_in[8];   // [3]
    const float* Wa     = (const float*)d_in[9];   // [10][10]
    const float* ba     = (const float*)d_in[10];  // [10]
    const float* Wo     = (const float*)d_in[11];  // [3][20][20]
    const float* bo     = (const float*)d_in[12];  // [3][20]
    const float* Wi     = (const float*)d_in[13];  // [2][20]
    const float* bi     = (const float*)d_in[14];  // [2]
    float* out = (float*)d_out;
    float* ws  = (float*)d_ws;

    float* xs0   = ws;                       // 40960   SoA [10][4096]
    float* xs1   = ws + 40960;               // 40960
    float* xs2   = ws + 81920;               // 40960
    float* hs0   = ws + 122880;              // 40960   SoA planes
    float* hs1   = ws + 163840;              // 40960
    float* hs2   = ws + 204800;              // 40960
    float* part0 = ws + 245760;              // 163840  SoA [4][10][4096]
    float* part1 = ws + 409600;              // 163840
    float* part2 = ws + 573440;              // 163840
    float* ta    = ws + 737280;              // 655360
    float* tb    = ws + 1392640;             // 655360
    float* hpb   = ta;                       // alias: ta dead after F1 reads it
    float* att_part = ws + 2048000;          // 640
    unsigned int* ticket = (unsigned int*)(ws + 2048640);

    hipMemsetAsync(ticket, 0, sizeof(unsigned int), stream);

    // K0: embed gather once (tiny) -> xs0 + hs0 planes
    gnn_embed<<<N_ATOMS / 128, 128, 0, stream>>>(fp, emb_fp, Wg, bg, xs0, hs0);

    // F0: conv-L0 || gnn-L0 (hs0 read from L2-resident planes)
    fused_layer<<<TOTAL_BLOCKS, 256, 0, stream>>>(
        A, hs0, part0,
        nullptr, words, emb_w, Wc, bc, ta, nullptr, nullptr, nullptr);

    // P1: xs1 = xs0 + sum part0 ; hs1 = relu(W1 xs1 + b1)
    gnn_prep<<<N_ATOMS / 128, 128, 0, stream>>>(
        xs0, part0, Wg + 100, bg + 10, xs1, hs1);

    // F1: conv-L1 || gnn-L1
    fused_layer<<<TOTAL_BLOCKS, 256, 0, stream>>>(
        A, hs1, part1,
        ta, words, emb_w, Wc + 529, bc + 1, tb, nullptr, nullptr, nullptr);

    // P2: xs2 = xs1 + sum part1 ; hs2 = relu(W2 xs2 + b2)
    gnn_prep<<<N_ATOMS / 128, 128, 0, stream>>>(
        xs1, part1, Wg + 200, bg + 20, xs2, hs2);

    // F2: conv-L2 (+ fused hp) || gnn-L2
    fused_layer<<<TOTAL_BLOCKS, 256, 0, stream>>>(
        A, hs2, part2,
        tb, words, emb_w, Wc + 1058, bc + 2, nullptr, Wa, ba, hpb);

    // ATTN (+ comp in-block, + final MLP in last-arriving block)
    attn_final<<<ATT_BLOCKS, 1024, 0, stream>>>(
        xs2, part2, hpb, Wa, ba, Wo, bo, Wi, bi, att_part, ticket, out);
}